// Round 11
// baseline (25.012 us; speedup 1.0000x reference)
//
#include <hip/hip_runtime.h>
#include <stdint.h>

typedef _Float16 f16;
typedef f16   f16x2 __attribute__((ext_vector_type(2)));
typedef f16   f16x8 __attribute__((ext_vector_type(8)));
typedef float f32x4 __attribute__((ext_vector_type(4)));

static constexpr int M_ = 64;
static constexpr int K_ = 4096;
static constexpr int N_ = 14336;

// x fp32 [64][4096] -> f16, tiled into MFMA-fragment order:
// f16x8-slot ((kg*4+mt)*64 + h*16 + l16) holds x[mt*16+l16][(kg*4+h)*8 .. +8)
__global__ void xconv_kernel(const float* __restrict__ x, uint4* __restrict__ xt) {
    int t = blockIdx.x * blockDim.x + threadIdx.x;      // 32768 threads
    int row = t >> 9, kb = t & 511;
    int kg = kb >> 2, h = kb & 3, mt = row >> 4, l16 = row & 15;
    int dst = (kg * 4 + mt) * 64 + h * 16 + l16;
    const float4* p = reinterpret_cast<const float4*>(x) + 2 * (size_t)t;   // coalesced read
    float4 a = p[0], b = p[1];
    union { f16x8 h8; uint4 v; } z;
    z.h8[0] = (f16)a.x; z.h8[1] = (f16)a.y; z.h8[2] = (f16)a.z; z.h8[3] = (f16)a.w;
    z.h8[4] = (f16)b.x; z.h8[5] = (f16)b.y; z.h8[6] = (f16)b.z; z.h8[7] = (f16)b.w;
    xt[dst] = z.v;
}

// nibble->f16 dequant: 0x6400|n = 1024+n exact; pk_add(-1032) -> n-8 exact; pk_mul(s).
// packed dword nibble p -> frag slot 2p, nibble p+4 -> slot 2p+1 (folds pack-perm).
__device__ __forceinline__ f16x8 dequant(uint u, f16x2 sc) {
    const f16 m = (f16)(-1032.0f);
    const f16x2 mc = {m, m};
    union { f16x2 h2; uint uu; } um;
    union { f16x2 h2[4]; f16x8 v; } ob;
    #pragma unroll
    for (int p = 0; p < 4; ++p) {
        um.uu = 0x64006400u | ((u >> (4 * p)) & 0x000F000Fu);
        ob.h2[p] = (um.h2 + mc) * sc;
    }
    return ob.v;
}

// grid=448 (BN=32), block=512=8 waves. Wave w owns K-chunk [w*512,(w+1)*512).
// B: global->reg (dwordx4) -> ds_write_b128 -> ds_read b32, all wave-private,
// no barriers / no global_load_lds / no inline asm in the main loop.
// A: fragment-tiled xt, DEPTH-3 ring register pipeline (ap[L%3], capture-then-
// refill same slot, all indices compile-time). acc 4mt x 2nt.
template<bool PRE>
__global__ __launch_bounds__(512, 4)
void gemm_kernel(const float* __restrict__ xf, const f16x8* __restrict__ xt8,
                 const uint* __restrict__ bpk, const float* __restrict__ s,
                 float* __restrict__ out)
{
    __shared__ __align__(16) uint lbs[16384];           // 64 KB (B: 32 KB, epilogue: 64 KB)
    const int tid  = threadIdx.x;
    const int lane = tid & 63;
    const int w    = tid >> 6;                          // K-chunk id 0..7
    const int h    = lane >> 4;
    const int l16  = lane & 15;
    const int n0   = blockIdx.x * 32;

    f16x2 sc0[4], sc1[4];                               // per-group scales (const-indexed)
    #pragma unroll
    for (int g = 0; g < 4; ++g) {
        float a = s[(size_t)(w * 4 + g) * N_ + n0 + l16];
        float b = s[(size_t)(w * 4 + g) * N_ + n0 + 16 + l16];
        f16 ha = (f16)a, hb = (f16)b;
        sc0[g] = f16x2{ha, ha};
        sc1[g] = f16x2{hb, hb};
    }

#define LOADB(G, R0, R1)                                                              \
    {                                                                                 \
        const uint* p0_ = bpk + (size_t)(n0 +      l16) * 512 + w * 64 + (G) * 16 + h * 4; \
        const uint* p1_ = bpk + (size_t)(n0 + 16 + l16) * 512 + w * 64 + (G) * 16 + h * 4; \
        R0 = *reinterpret_cast<const uint4*>(p0_);                                    \
        R1 = *reinterpret_cast<const uint4*>(p1_);                                    \
    }
#define WRITEB(BUF, R0, R1)                                                           \
    {                                                                                 \
        uint4* d_ = reinterpret_cast<uint4*>(lbs + w * 1024 + (BUF) * 512) + lane;    \
        d_[0] = R0; d_[64] = R1;                                                      \
    }
#define LOADA(DST, KS, MT)                                                                         \
    if constexpr (PRE) { DST = xt8[(size_t)(((w * 16 + (KS)) * 4 + (MT)) * 64 + lane)]; }          \
    else {                                                                                         \
        const float* xp_ = xf + (size_t)((MT) * 16 + l16) * K_ + (size_t)(w * 16 + (KS)) * 32 + h * 8; \
        float4 f0_ = *reinterpret_cast<const float4*>(xp_);                                        \
        float4 f1_ = *reinterpret_cast<const float4*>(xp_ + 4);                                    \
        f16x8 av_;                                                                                 \
        av_[0] = (f16)f0_.x; av_[1] = (f16)f0_.y; av_[2] = (f16)f0_.z; av_[3] = (f16)f0_.w;        \
        av_[4] = (f16)f1_.x; av_[5] = (f16)f1_.y; av_[6] = (f16)f1_.z; av_[7] = (f16)f1_.w;        \
        DST = av_;                                                                                 \
    }

    uint4 tE0, tE1, tO0, tO1;                           // named B transit
    LOADB(0, tE0, tE1)
    LOADB(1, tO0, tO1)
    WRITEB(0, tE0, tE1)                                 // stage group 0 (one-time stall)

    f16x8 ap[3][4];                                     // ring-3 A pipeline (const-indexed)
    #pragma unroll
    for (int mt = 0; mt < 4; ++mt) { LOADA(ap[0][mt], 0, mt) }
    #pragma unroll
    for (int mt = 0; mt < 4; ++mt) { LOADA(ap[1][mt], 1, mt) }
    #pragma unroll
    for (int mt = 0; mt < 4; ++mt) { LOADA(ap[2][mt], 2, mt) }

    f32x4 acc[2][4];
    #pragma unroll
    for (int nt = 0; nt < 2; ++nt)
        #pragma unroll
        for (int mt = 0; mt < 4; ++mt) acc[nt][mt] = f32x4{0.f, 0.f, 0.f, 0.f};

    // capture A for k-step L=(G*4+T) from slot L%3, then refill SAME slot with L+3
#define COMPUTE_T(G, T, U0, U1)                                                           \
    {                                                                                     \
        const f16x8 a0_ = ap[((G) * 4 + (T)) % 3][0];                                     \
        const f16x8 a1_ = ap[((G) * 4 + (T)) % 3][1];                                     \
        const f16x8 a2_ = ap[((G) * 4 + (T)) % 3][2];                                     \
        const f16x8 a3_ = ap[((G) * 4 + (T)) % 3][3];                                     \
        if ((G) * 4 + (T) + 3 < 16) {                                                     \
            LOADA(ap[((G) * 4 + (T)) % 3][0], (G) * 4 + (T) + 3, 0)                       \
            LOADA(ap[((G) * 4 + (T)) % 3][1], (G) * 4 + (T) + 3, 1)                       \
            LOADA(ap[((G) * 4 + (T)) % 3][2], (G) * 4 + (T) + 3, 2)                       \
            LOADA(ap[((G) * 4 + (T)) % 3][3], (G) * 4 + (T) + 3, 3)                       \
        }                                                                                 \
        const f16x8 b0_ = dequant(U0, sc0[(G)]);                                          \
        const f16x8 b1_ = dequant(U1, sc1[(G)]);                                          \
        acc[0][0] = __builtin_amdgcn_mfma_f32_16x16x32_f16(a0_, b0_, acc[0][0], 0, 0, 0); \
        acc[0][1] = __builtin_amdgcn_mfma_f32_16x16x32_f16(a1_, b0_, acc[0][1], 0, 0, 0); \
        acc[0][2] = __builtin_amdgcn_mfma_f32_16x16x32_f16(a2_, b0_, acc[0][2], 0, 0, 0); \
        acc[0][3] = __builtin_amdgcn_mfma_f32_16x16x32_f16(a3_, b0_, acc[0][3], 0, 0, 0); \
        acc[1][0] = __builtin_amdgcn_mfma_f32_16x16x32_f16(a0_, b1_, acc[1][0], 0, 0, 0); \
        acc[1][1] = __builtin_amdgcn_mfma_f32_16x16x32_f16(a1_, b1_, acc[1][1], 0, 0, 0); \
        acc[1][2] = __builtin_amdgcn_mfma_f32_16x16x32_f16(a2_, b1_, acc[1][2], 0, 0, 0); \
        acc[1][3] = __builtin_amdgcn_mfma_f32_16x16x32_f16(a3_, b1_, acc[1][3], 0, 0, 0); \
    }

#define GROUP(G, WBUF, WR0, WR1, DOWRITE)                                             \
    {                                                                                 \
        const int rb_ = w * 1024 + ((G) & 1) * 512 + l16 * 4 + h;                     \
        const uint u00_ = lbs[rb_ +   0], u01_ = lbs[rb_ +  64];                      \
        const uint u02_ = lbs[rb_ + 128], u03_ = lbs[rb_ + 192];                      \
        const uint u10_ = lbs[rb_ + 256], u11_ = lbs[rb_ + 320];                      \
        const uint u12_ = lbs[rb_ + 384], u13_ = lbs[rb_ + 448];                      \
        COMPUTE_T(G, 0, u00_, u10_)                                                   \
        if (DOWRITE) { WRITEB(WBUF, WR0, WR1) }                                       \
        COMPUTE_T(G, 1, u01_, u11_)                                                   \
        COMPUTE_T(G, 2, u02_, u12_)                                                   \
        COMPUTE_T(G, 3, u03_, u13_)                                                   \
    }

    { LOADB(2, tE0, tE1) }                              // issue g2 ~1.5 groups early
    GROUP(0, 1, tO0, tO1, true)                         // compute g0, stage g1
    { LOADB(3, tO0, tO1) }                              // issue g3
    GROUP(1, 0, tE0, tE1, true)                         // compute g1, stage g2
    GROUP(2, 1, tO0, tO1, true)                         // compute g2, stage g3
    GROUP(3, 0, tE0, tE1, false)                        // compute g3 (no more staging)

#undef GROUP
#undef COMPUTE_T
#undef LOADA
#undef WRITEB
#undef LOADB

    // ---- epilogue: flat LDS exchange of the 8 K-partials ----
    __syncthreads();
    f32x4* red = reinterpret_cast<f32x4*>(lbs);
    #pragma unroll
    for (int nt = 0; nt < 2; ++nt)
        #pragma unroll
        for (int mt = 0; mt < 4; ++mt)
            red[(w * 8 + nt * 4 + mt) * 64 + lane] = acc[nt][mt];
    __syncthreads();
    {
        f32x4 v = red[(0 * 8 + w) * 64 + lane];
        v += red[(1 * 8 + w) * 64 + lane];
        v += red[(2 * 8 + w) * 64 + lane];
        v += red[(3 * 8 + w) * 64 + lane];
        v += red[(4 * 8 + w) * 64 + lane];
        v += red[(5 * 8 + w) * 64 + lane];
        v += red[(6 * 8 + w) * 64 + lane];
        v += red[(7 * 8 + w) * 64 + lane];
        const int nt = w >> 2, mt = w & 3;
        #pragma unroll
        for (int q = 0; q < 4; ++q)
            out[(size_t)(mt * 16 + h * 4 + q) * N_ + (n0 + nt * 16 + l16)] = v[q];
    }
}

extern "C" void kernel_launch(void* const* d_in, const int* in_sizes, int n_in,
                              void* d_out, int out_size, void* d_ws, size_t ws_size,
                              hipStream_t stream) {
    const float* x   = (const float*)d_in[0];
    const uint*  bpk = (const uint*)d_in[1];
    const float* s   = (const float*)d_in[2];
    float*       out = (float*)d_out;

    if (ws_size >= (size_t)(M_ * K_ * 2)) {
        xconv_kernel<<<128, 256, 0, stream>>>(x, (uint4*)d_ws);
        gemm_kernel<true><<<448, 512, 0, stream>>>(x, (const f16x8*)d_ws, bpk, s, out);
    } else {
        gemm_kernel<false><<<448, 512, 0, stream>>>(x, nullptr, bpk, s, out);
    }
}